// Round 8
// baseline (428.785 us; speedup 1.0000x reference)
//
#include <hip/hip_runtime.h>

// Problem constants (reference: BATCH=65536, SEQ_LEN=1024, M=32, DEGREE=7 -> D=8)
#define MM 32
#define DD 8
#define LL 1024
#define NBATCH 65536
#define NBLK 2048
#define RPB (NBATCH / NBLK)   // 32 rows per block
#define RPP 4                 // rows per phase (per barrier)
#define NPH (RPB / RPP)       // 8 phases per block

// Folded solve weights: Wt[i][d][j] = (Ginv_i * V_i^T)[d][j]. 32 KB, recomputed
// every launch (graph-capture safe), L2-resident for the main kernel.
// Layout: g_Wt[(i*8+d)*32 + j] so thread t=(i*8+d) reads a linear 128-B slab.
__device__ float g_Wt[MM * DD * MM];

// ---------------------------------------------------------------------------
// Kernel 1: build Chebyshev Vandermonde per row-group i, form 8x8 Gram in
// fp64, Gauss-Jordan invert, fold: Wt[i][d][j] = sum_e Ginv[d][e] * V[j][e].
// ---------------------------------------------------------------------------
__global__ void precompute_w_kernel(const float* __restrict__ tg) {
    const int i = blockIdx.x;
    const int t = threadIdx.x;

    __shared__ float  V[MM][DD];        // V[j][e]
    __shared__ double A[DD][2 * DD];    // Gauss-Jordan augmented [G | I]

    if (t < MM) {
        float tt = tg[t * MM + i];      // times[i][j] = tg[j*32 + i]
        float c0 = 1.0f, c1 = tt;
        V[t][0] = c0;
        V[t][1] = c1;
        for (int e = 2; e < DD; ++e) {
            float c2 = 2.0f * tt * c1 - c0;
            V[t][e] = c2;
            c0 = c1; c1 = c2;
        }
    }
    __syncthreads();

    {
        int d = t >> 3, e = t & 7;
        double s = 0.0;
        for (int j = 0; j < MM; ++j) s += (double)V[j][d] * (double)V[j][e];
        A[d][e] = s;
        A[d][DD + e] = (d == e) ? 1.0 : 0.0;
    }
    __syncthreads();

    if (t == 0) {
        for (int p = 0; p < DD; ++p) {
            double inv = 1.0 / A[p][p];
            for (int c = p; c < 2 * DD; ++c) A[p][c] *= inv;
            for (int r2 = 0; r2 < DD; ++r2) {
                if (r2 == p) continue;
                double f = A[r2][p];
                for (int c = p; c < 2 * DD; ++c) A[r2][c] -= f * A[p][c];
            }
        }
    }
    __syncthreads();

    for (int k = t; k < DD * MM; k += 64) {
        int d = k >> 5;
        int j = k & 31;
        double s = 0.0;
        for (int e = 0; e < DD; ++e) s += A[d][DD + e] * (double)V[j][e];
        g_Wt[(i * DD + d) * MM + j] = (float)s;
    }
}

// ---------------------------------------------------------------------------
// Kernel 2: thread t = (i = t>>3, d = t&7).
// Phase = 4 rows between barriers, double-buffered in LDS:
//   - prefetch phase k+2's 4 rows into regs (4 x 1-KB-per-wave float4 loads
//     in flight per wave -> 64 KB/CU outstanding, covers ~900-cyc HBM lat),
//   - ds_write phase k+1's regs into the other buffer (loaded a full phase
//     ago -> vmcnt satisfied, no stall),
//   - compute 4 rows from current buffer: 32 register weights x padded-LDS
//     broadcast reads (<=2-way banks, free), store 256 contiguous dwords/row.
// Padded LDS index for element l: l + 4*(l>>5)  ->  (j,i) at j*36 + i.
// ---------------------------------------------------------------------------
__global__ __launch_bounds__(256, 4) void poly_apply_kernel(
        const float* __restrict__ x,
        float* __restrict__ out) {
    __shared__ float xl[2][RPP][1156];   // 2 x 4 x 4.52 KB = 36.1 KB

    const int t = threadIdx.x;      // 0..255
    const int i = t >> 3;           // 0..31

    // Preload this thread's 32 weights (128 B, linear): w[j] = Wt[i][d][j]
    float w[32];
    {
        const float4* wp = (const float4*)g_Wt + t * 8;
#pragma unroll
        for (int q = 0; q < 8; ++q) {
            float4 v4 = wp[q];
            w[4 * q + 0] = v4.x;
            w[4 * q + 1] = v4.y;
            w[4 * q + 2] = v4.z;
            w[4 * q + 3] = v4.w;
        }
    }

    const int r0 = blockIdx.x * RPB;
    const int staddr = 4 * t + 4 * (t >> 3);                     // padded word addr for l=4t
    const float4* xr = (const float4*)(x + (size_t)r0 * LL) + t; // +256 float4 per row

    float4 v[RPP];

    // Prologue: stage phase 0 into buf 0; prefetch phase 1 into regs.
#pragma unroll
    for (int q = 0; q < RPP; ++q) v[q] = xr[q * 256];
#pragma unroll
    for (int q = 0; q < RPP; ++q) *(float4*)&xl[0][q][staddr] = v[q];
#pragma unroll
    for (int q = 0; q < RPP; ++q) v[q] = xr[(RPP + q) * 256];
    __syncthreads();

    for (int ph = 0; ph < NPH; ++ph) {
        const int p = ph & 1;

        // Write phase ph+1's rows (in regs since one phase ago) to buffer p^1;
        // prev-phase barrier protects p^1's old readers.
        if (ph + 1 < NPH) {
#pragma unroll
            for (int q = 0; q < RPP; ++q) *(float4*)&xl[p ^ 1][q][staddr] = v[q];
        }
        // Prefetch phase ph+2 into regs.
        if (ph + 2 < NPH) {
#pragma unroll
            for (int q = 0; q < RPP; ++q)
                v[q] = xr[(size_t)((ph + 2) * RPP + q) * 256];
        }

        // Compute the 4 rows of phase ph from buffer p.
#pragma unroll
        for (int rr = 0; rr < RPP; ++rr) {
            const float* xb = &xl[p][rr][i];
            float acc = 0.f;
#pragma unroll
            for (int j = 0; j < 32; ++j)
                acc = fmaf(w[j], xb[j * 36], acc);
            out[(size_t)(r0 + ph * RPP + rr) * 256 + t] = acc;
        }

        __syncthreads();   // buf p reads done; buf p^1 writes visible
    }
}

extern "C" void kernel_launch(void* const* d_in, const int* in_sizes, int n_in,
                              void* d_out, int out_size, void* d_ws, size_t ws_size,
                              hipStream_t stream) {
    const float* x  = (const float*)d_in[0];   // [65536, 1024] f32
    const float* tg = (const float*)d_in[1];   // [1024] f32
    float* out = (float*)d_out;                // [65536, 32, 8] f32
    (void)d_ws; (void)ws_size;

    precompute_w_kernel<<<32, 64, 0, stream>>>(tg);
    poly_apply_kernel<<<NBLK, 256, 0, stream>>>(x, out);
}

// Round 9
// 397.073 us; speedup vs baseline: 1.0799x; 1.0799x over previous
//
#include <hip/hip_runtime.h>

// Problem constants (reference: BATCH=65536, SEQ_LEN=1024, M=32, DEGREE=7 -> D=8)
#define MM 32
#define DD 8
#define LL 1024
#define NBATCH 65536
#define NBLK 2048
#define RPB (NBATCH / NBLK)   // 32 rows per block
#define NPASS (RPB / 2)       // 16 passes of 2 rows

// Folded solve weights: Wt[i][d][j] = (Ginv_i * V_i^T)[d][j]. 32 KB, recomputed
// every launch (graph-capture safe), L2-resident for the main kernel.
__device__ float g_Wt[MM * DD * MM];

// ---------------------------------------------------------------------------
// Kernel 1: build Chebyshev Vandermonde per row-group i, form 8x8 Gram in
// fp64, Gauss-Jordan invert, fold: Wt[i][d][j] = sum_e Ginv[d][e] * V[j][e].
// ---------------------------------------------------------------------------
__global__ void precompute_w_kernel(const float* __restrict__ tg) {
    const int i = blockIdx.x;
    const int t = threadIdx.x;

    __shared__ float  V[MM][DD];        // V[j][e]
    __shared__ double A[DD][2 * DD];    // Gauss-Jordan augmented [G | I]

    if (t < MM) {
        float tt = tg[t * MM + i];      // times[i][j] = tg[j*32 + i]
        float c0 = 1.0f, c1 = tt;
        V[t][0] = c0;
        V[t][1] = c1;
        for (int e = 2; e < DD; ++e) {
            float c2 = 2.0f * tt * c1 - c0;
            V[t][e] = c2;
            c0 = c1; c1 = c2;
        }
    }
    __syncthreads();

    {
        int d = t >> 3, e = t & 7;
        double s = 0.0;
        for (int j = 0; j < MM; ++j) s += (double)V[j][d] * (double)V[j][e];
        A[d][e] = s;
        A[d][DD + e] = (d == e) ? 1.0 : 0.0;
    }
    __syncthreads();

    if (t == 0) {
        for (int p = 0; p < DD; ++p) {
            double inv = 1.0 / A[p][p];
            for (int c = p; c < 2 * DD; ++c) A[p][c] *= inv;
            for (int r2 = 0; r2 < DD; ++r2) {
                if (r2 == p) continue;
                double f = A[r2][p];
                for (int c = p; c < 2 * DD; ++c) A[r2][c] -= f * A[p][c];
            }
        }
    }
    __syncthreads();

    for (int k = t; k < DD * MM; k += 64) {
        int d = k >> 5;
        int j = k & 31;
        double s = 0.0;
        for (int e = 0; e < DD; ++e) s += A[d][DD + e] * (double)V[j][e];
        g_Wt[(i * DD + d) * MM + j] = (float)s;
    }
}

// ---------------------------------------------------------------------------
// Kernel 2: LDS-issue-optimized.
// Pass = 2 rows, ping-pong double buffer, 1 barrier/pass.
//  Staging (thread -> (srs=t>>7, si=(t&127)&31, sq=(t&127)>>5)):
//    8x coalesced global b32 loads (two full 128-B lines per instr) into regs,
//    written next pass as 4x ds_write_b64 into TRANSPOSED layout
//    xT[row][si*36 + 8*sq + c]  (j contiguous per i; i-stride 36 words).
//  Compute (thread -> (srs, ci=(t&127)>>2, dp=t&3)): 2 d's per thread,
//    64 register weights; per row 8x ds_read_b128 of xT[ci*36 + 4m]
//    (4-way broadcast over dp, 2-way banks over ci -> free), 64 FMA,
//    one float2 store (wave = contiguous 512 B).
// LDS instr budget/CU ~35 us < HBM ~53 us floor.
// ---------------------------------------------------------------------------
__global__ __launch_bounds__(256, 4) void poly_apply_kernel(
        const float* __restrict__ x,
        float* __restrict__ out) {
    __shared__ __align__(16) float xT[2][2][1152];   // [buf][row][32*36] = 18.4 KB

    const int t   = threadIdx.x;
    const int rs  = t >> 7;          // row-in-pass 0/1 (staging AND compute)
    const int tt  = t & 127;
    const int si  = tt & 31;         // staging i
    const int sq  = tt >> 5;         // staging j-octet 0..3
    const int ci  = tt >> 2;         // compute i 0..31
    const int dp  = t & 3;           // compute d-pair 0..3

    // Weights: w0[j]=Wt[ci][2dp][j], w1[j]=Wt[ci][2dp+1][j] (64 VGPRs, 256-B slab)
    float w0[32], w1[32];
    {
        const float4* wp = (const float4*)g_Wt + (ci * DD + 2 * dp) * 8;
#pragma unroll
        for (int q = 0; q < 8; ++q) {
            float4 a = wp[q];
            w0[4 * q + 0] = a.x; w0[4 * q + 1] = a.y;
            w0[4 * q + 2] = a.z; w0[4 * q + 3] = a.w;
            float4 b = wp[q + 8];
            w1[4 * q + 0] = b.x; w1[4 * q + 1] = b.y;
            w1[4 * q + 2] = b.z; w1[4 * q + 3] = b.w;
        }
    }
#pragma unroll
    for (int j = 0; j < 32; ++j) {
        asm volatile("" : "+v"(w0[j]));
        asm volatile("" : "+v"(w1[j]));
    }

    const int r0 = blockIdx.x * RPB;
    // staging base: row (r0 + 2p + rs), element si + 256*sq + 32*c
    const float* xbase = x + (size_t)(r0 + rs) * LL + si + 256 * sq;
    const int wboff = si * 36 + 8 * sq;   // LDS word offset for this thread's octet

    float v[8];

    // Prologue: pass0 -> buf0; prefetch pass1 into regs.
#pragma unroll
    for (int c = 0; c < 8; ++c) v[c] = xbase[32 * c];
    {
        float* wb = &xT[0][rs][wboff];
#pragma unroll
        for (int k = 0; k < 4; ++k) {
            float2 p2; p2.x = v[2 * k]; p2.y = v[2 * k + 1];
            *(float2*)&wb[2 * k] = p2;
        }
    }
#pragma unroll
    for (int c = 0; c < 8; ++c) v[c] = xbase[2 * LL + 32 * c];
    __syncthreads();

    for (int p = 0; p < NPASS; ++p) {
        // Write pass p+1 (in regs since last pass) into the other buffer.
        if (p + 1 < NPASS) {
            float* wb = &xT[(p + 1) & 1][rs][wboff];
#pragma unroll
            for (int k = 0; k < 4; ++k) {
                float2 p2; p2.x = v[2 * k]; p2.y = v[2 * k + 1];
                *(float2*)&wb[2 * k] = p2;
            }
        }
        // Prefetch pass p+2.
        if (p + 2 < NPASS) {
#pragma unroll
            for (int c = 0; c < 8; ++c)
                v[c] = xbase[(size_t)(p + 2) * 2 * LL + 32 * c];
        }

        // Compute row (r0 + 2p + rs) from buf[p&1].
        {
            const float* xb = &xT[p & 1][rs][ci * 36];
            float a0 = 0.f, a1 = 0.f;
#pragma unroll
            for (int m = 0; m < 8; ++m) {
                float4 xq = *(const float4*)&xb[4 * m];
                a0 = fmaf(w0[4 * m + 0], xq.x, a0);
                a1 = fmaf(w1[4 * m + 0], xq.x, a1);
                a0 = fmaf(w0[4 * m + 1], xq.y, a0);
                a1 = fmaf(w1[4 * m + 1], xq.y, a1);
                a0 = fmaf(w0[4 * m + 2], xq.z, a0);
                a1 = fmaf(w1[4 * m + 2], xq.z, a1);
                a0 = fmaf(w0[4 * m + 3], xq.w, a0);
                a1 = fmaf(w1[4 * m + 3], xq.w, a1);
            }
            float2 o; o.x = a0; o.y = a1;
            *(float2*)&out[(size_t)(r0 + 2 * p + rs) * 256 + ci * 8 + 2 * dp] = o;
        }

        __syncthreads();   // buf[p&1] reads done; buf[(p+1)&1] writes visible
    }
}

extern "C" void kernel_launch(void* const* d_in, const int* in_sizes, int n_in,
                              void* d_out, int out_size, void* d_ws, size_t ws_size,
                              hipStream_t stream) {
    const float* x  = (const float*)d_in[0];   // [65536, 1024] f32
    const float* tg = (const float*)d_in[1];   // [1024] f32
    float* out = (float*)d_out;                // [65536, 32, 8] f32
    (void)d_ws; (void)ws_size;

    precompute_w_kernel<<<32, 64, 0, stream>>>(tg);
    poly_apply_kernel<<<NBLK, 256, 0, stream>>>(x, out);
}